// Round 2
// baseline (539.689 us; speedup 1.0000x reference)
//
#include <hip/hip_runtime.h>

// RelativePositionEncoding: out[b,i,j,:] = W[idx_res] + W[66+idx_tok]
//                                        + ment * W[132] + W[133+idx_chain]
// One-hot structure of the 139-dim concat feature makes the einsum a sum of
// 3-4 rows of W. Integer-valued feats => argmin-onehot == clamped int.
//
// Layout: 32 lanes per (i,j) pair, each lane owns one float4 of the 128
// channels (16B/lane coalesced stores). Write-streaming bound: 512 MiB out.

typedef float f4 __attribute__((ext_vector_type(4)));  // native vector: OK for nontemporal builtin

#define NCH4 32  // 128 channels / 4 per float4

__global__ __launch_bounds__(256) void relpos_kernel(
    const float* __restrict__ feats,  // [n, 10]
    const f4* __restrict__ W4,        // [139, 32] as float4
    f4* __restrict__ out4,            // [n*n, 32] as float4
    int n, long total4)
{
    const long tid = (long)blockIdx.x * blockDim.x + threadIdx.x;
    if (tid >= total4) return;
    const int r = (int)(tid >> 5);   // pair index i*n + j
    const int c = (int)(tid & 31);   // float4 channel index

    const int i = r / n;
    const int j = r - i * n;

    const float* fi = feats + i * 10;
    const float* fj = feats + j * 10;
    const float res_i = fi[0], tok_i = fi[1], asym_i = fi[2], ent_i = fi[3], sym_i = fi[4];
    const float res_j = fj[0], tok_j = fj[1], asym_j = fj[2], ent_j = fj[3], sym_j = fj[4];

    const float dres = res_i - res_j;
    const float dtok = tok_i - tok_j;
    const float dsym = sym_i - sym_j;
    const bool same_chain = (asym_i == asym_j);
    const bool same_res   = (dres == 0.0f);
    const float ment      = (ent_i == ent_j) ? 1.0f : 0.0f;

    // nearest-bin == clamped integer (feats are integer-valued)
    const float dr = fminf(fmaxf(dres + 32.0f, 0.0f), 64.0f);
    const int idx_res = same_chain ? (int)dr : 65;
    const float dt = fminf(fmaxf(dtok + 32.0f, 0.0f), 64.0f);
    const int idx_tok = (same_chain && same_res) ? (int)dt : 65;
    const float dc = fminf(fmaxf(dsym + 2.0f, 0.0f), 4.0f);
    const int idx_chain = (!same_chain) ? (int)dc : 5;

    const f4 a = W4[idx_res * NCH4 + c];
    const f4 b = W4[(66 + idx_tok) * NCH4 + c];
    const f4 e = W4[132 * NCH4 + c];
    const f4 d = W4[(133 + idx_chain) * NCH4 + c];

    const f4 o = a + b + ment * e + d;

    __builtin_nontemporal_store(o, &out4[(long)r * NCH4 + c]);
}

extern "C" void kernel_launch(void* const* d_in, const int* in_sizes, int n_in,
                              void* d_out, int out_size, void* d_ws, size_t ws_size,
                              hipStream_t stream) {
    const float* feats = (const float*)d_in[0];
    const f4* W4       = (const f4*)d_in[1];
    f4* out4           = (f4*)d_out;

    const int n = in_sizes[0] / 10;          // b=1, [1,n,10]
    const long total4 = (long)n * n * NCH4;  // one thread per float4 of output
    const int block = 256;
    const long grid = (total4 + block - 1) / block;

    relpos_kernel<<<dim3((unsigned)grid), dim3(block), 0, stream>>>(
        feats, W4, out4, n, total4);
}